// Round 8
// baseline (86.161 us; speedup 1.0000x reference)
//
#include <hip/hip_runtime.h>
#include <cmath>

#define IMG_W 1024
#define SROWS 22              // staged source rows  (16 outputs + 6 halo)
#define SCOLS 70              // staged source cols  (64 outputs + 6 halo)
#define NBLOCKS 1024          // 16 x 64 grid
#define NSLOTS 64             // padded accumulation slots (64B apart)

// separable Gaussian: w(ky,kx) = gv[ky]*gh[kx], 1/(8*pi) folded into gv
struct GK { float gh[7]; float gv[7]; };

__global__ __launch_bounds__(256)
void mind_tile(const float* __restrict__ img1, const float* __restrict__ img2,
               float* __restrict__ ws, float* __restrict__ out, GK gk)
{
    __shared__ float4 s1[SROWS * SCOLS];    // raw pointwise fields   (24640 B)
    __shared__ float4 s2[SROWS * 64];       // h-convolved fields     (22528 B)
    __shared__ float  wsum[4];
    __shared__ int    lastflag;

    const int tx  = (int)threadIdx.x;       // 0..63 : output col owner
    const int ty  = (int)threadIdx.y;       // 0..3  : wave id / 4-row group owner
    const int tid = ty * 64 + tx;
    const int x0  = 7 + 64 * (int)blockIdx.x;   // first output col of tile
    const int y0  = 7 + 16 * (int)blockIdx.y;   // first output row of tile

    // ---- stage 1: pointwise fields -> LDS ----
    #pragma unroll
    for (int k = 0; k < 7; ++k) {
        const int e = tid + 256 * k;
        if (e < SROWS * SCOLS) {
            const int r  = e / SCOLS;
            const int c  = e - r * SCOLS;
            const int sr = min(y0 - 3 + r, 1023);   // clamp feeds only masked outputs
            const int sc = min(x0 - 3 + c, 1023);
            const int srp = sr ^ 512;               // the only in-bounds y-shift source
            const int scp = sc ^ 512;               // the only in-bounds x-shift source
            const float a  = img2[sr  * IMG_W + sc ];
            const float b  = img2[sr  * IMG_W + scp];
            const float cc = img2[srp * IMG_W + sc ];
            const float d  = img2[srp * IMG_W + scp];
            const float u  = img1[sr  * IMG_W + sc ];
            const float ub = img1[sr  * IMG_W + scp];
            const float uc = img1[srp * IMG_W + sc ];
            const float a2 = a * a;
            const float tb = a - b, tc = a - cc, td = a - d;
            const float su = u - ub, sv = u - uc;
            float4 f;
            f.x = fmaf(tb, tb, -a2);                      // H
            f.y = fmaf(tc, tc, -a2);                      // V
            f.z = fmaf(td, td, -a2);                      // D
            f.w = fmaf(u, u + u, fmaf(su, su, sv * sv));  // U (4*Vimg integrand)
            s1[e] = f;
        }
    }
    __syncthreads();

    // boundary-straddling detection (mask flips between col/row 511 and 512)
    const bool xs = (x0 - 3 <= 511) && (x0 + 66 >= 512);   // only bx==7
    const bool ys = (y0 - 3 <= 511) && (y0 + 18 >= 512);   // only by==31
    const bool xok = (x0 + tx <= 1016);
    float tsum = 0.f;

    if (!xs && !ys) {
        // ============ FAST path (92%): block-uniform masks, two-stage ==========
        // h-stage: each of the 22 rows h-convolved exactly ONCE (wave ty does
        // rows ty, ty+4, ...), result to s2.
        #pragma unroll
        for (int j = 0; j < 6; ++j) {
            const int r = ty + 4 * j;
            if (r < SROWS) {                         // wave-uniform predicate
                const float4* __restrict__ row = &s1[r * SCOLS + tx];
                float4 h = make_float4(0.f, 0.f, 0.f, 0.f);
                #pragma unroll
                for (int kx = 0; kx < 7; ++kx) {
                    const float4 g = row[kx];
                    h.x = fmaf(gk.gh[kx], g.x, h.x);
                    h.y = fmaf(gk.gh[kx], g.y, h.y);
                    h.z = fmaf(gk.gh[kx], g.z, h.z);
                    h.w = fmaf(gk.gh[kx], g.w, h.w);
                }
                s2[r * 64 + tx] = h;
            }
        }
        __syncthreads();

        // v-stage: read each needed s2 row once, register-reuse across 4 outputs
        float Px[4] = {0,0,0,0}, Py[4] = {0,0,0,0}, Pd[4] = {0,0,0,0}, V4[4] = {0,0,0,0};
        #pragma unroll
        for (int r = 0; r < 10; ++r) {
            const float4 h = s2[(4 * ty + r) * 64 + tx];
            #pragma unroll
            for (int o = 0; o < 4; ++o) {
                if (r - o >= 0 && r - o <= 6) {      // compile-time pruned
                    const float g = gk.gv[r - o];
                    Px[o] = fmaf(g, h.x, Px[o]);
                    Py[o] = fmaf(g, h.y, Py[o]);
                    Pd[o] = fmaf(g, h.z, Pd[o]);
                    V4[o] = fmaf(g, h.w, V4[o]);
                }
            }
        }
        #pragma unroll
        for (int o = 0; o < 4; ++o) {
            const float V = fmaf(V4[o], 0.25f, 1e-5f);
            const float invV = 1.0f / V;
            float M = fminf(0.f, Px[o]);
            M = fminf(M, Py[o]); M = fminf(M, Pd[o]);
            // 5 of 8 near-shift maps equal T0 here -> join the 72 far shifts
            const float pix = 77.f * __expf(M * invV)
                + __expf((M - Px[o]) * invV)
                + __expf((M - Py[o]) * invV)
                + __expf((M - Pd[o]) * invV);
            const bool ok = xok && (y0 + 4 * ty + o <= 1017);
            tsum += ok ? pix : 0.f;
        }
    } else {
        // ============ GENERAL path (79 blocks): one-stage, per-lane masks ======
        float glx[7], ghx[7];
        #pragma unroll
        for (int kx = 0; kx < 7; ++kx) {
            const bool lo = (((x0 - 3 + tx + kx) & 512) == 0);
            glx[kx] = lo ? gk.gh[kx] : 0.f;
            ghx[kx] = lo ? 0.f : gk.gh[kx];
        }
        float Ph[4]  = {0,0,0,0}, Qh[4]  = {0,0,0,0}, Pv[4] = {0,0,0,0}, Qv[4] = {0,0,0,0};
        float Ppp[4] = {0,0,0,0}, Ppm[4] = {0,0,0,0}, Pmp[4] = {0,0,0,0}, Pmm[4] = {0,0,0,0};
        float V4[4]  = {0,0,0,0};
        #pragma unroll
        for (int r = 0; r < 10; ++r) {
            const float4* __restrict__ row = &s1[(4 * ty + r) * SCOLS + tx];
            float hHlo = 0, hHhi = 0, hV = 0, hDlo = 0, hDhi = 0, hU = 0;
            #pragma unroll
            for (int kx = 0; kx < 7; ++kx) {
                const float4 g = row[kx];
                hHlo = fmaf(glx[kx],   g.x, hHlo);
                hHhi = fmaf(ghx[kx],   g.x, hHhi);
                hV   = fmaf(gk.gh[kx], g.y, hV);
                hDlo = fmaf(glx[kx],   g.z, hDlo);
                hDhi = fmaf(ghx[kx],   g.z, hDhi);
                hU   = fmaf(gk.gh[kx], g.w, hU);
            }
            const bool ylo = (((y0 + 4 * ty - 3 + r) & 512) == 0);
            #pragma unroll
            for (int o = 0; o < 4; ++o) {
                if (r - o >= 0 && r - o <= 6) {
                    const float g  = gk.gv[r - o];
                    const float wl = ylo ? g : 0.f;
                    const float wh = ylo ? 0.f : g;
                    Ph [o] = fmaf(g,  hHlo, Ph [o]);
                    Qh [o] = fmaf(g,  hHhi, Qh [o]);
                    Pv [o] = fmaf(wl, hV,   Pv [o]);
                    Qv [o] = fmaf(wh, hV,   Qv [o]);
                    Ppp[o] = fmaf(wl, hDlo, Ppp[o]);
                    Ppm[o] = fmaf(wh, hDlo, Ppm[o]);
                    Pmp[o] = fmaf(wl, hDhi, Pmp[o]);
                    Pmm[o] = fmaf(wh, hDhi, Pmm[o]);
                    V4 [o] = fmaf(g,  hU,   V4 [o]);
                }
            }
        }
        #pragma unroll
        for (int o = 0; o < 4; ++o) {
            const float V = fmaf(V4[o], 0.25f, 1e-5f);
            const float invV = 1.0f / V;
            float M = fminf(0.f, Ph[o]);
            M = fminf(M, Qh[o]);  M = fminf(M, Pv[o]);  M = fminf(M, Qv[o]);
            M = fminf(M, Ppp[o]); M = fminf(M, Pmp[o]); M = fminf(M, Ppm[o]); M = fminf(M, Pmm[o]);
            const float pix = 72.f * __expf(M * invV)
                + __expf((M - Ph [o]) * invV) + __expf((M - Qh [o]) * invV)
                + __expf((M - Pv [o]) * invV) + __expf((M - Qv [o]) * invV)
                + __expf((M - Ppp[o]) * invV) + __expf((M - Pmp[o]) * invV)
                + __expf((M - Ppm[o]) * invV) + __expf((M - Pmm[o]) * invV);
            const bool ok = xok && (y0 + 4 * ty + o <= 1017);
            tsum += ok ? pix : 0.f;
        }
    }

    // ---- block reduction ----
    #pragma unroll
    for (int off = 32; off > 0; off >>= 1)
        tsum += __shfl_down(tsum, off, 64);
    if (tx == 0) wsum[ty] = tsum;
    __syncthreads();

    // ---- grid reduction: 64 padded slots + last-block ticket (no 2nd kernel) --
    // ws layout (zeroed by memsetAsync): slots at ws[16*i] (64B apart), i<64;
    // ticket counter at ws[1024].
    if (tid == 0) {
        const float bt = wsum[0] + wsum[1] + wsum[2] + wsum[3];
        const int bid = (int)blockIdx.y * gridDim.x + (int)blockIdx.x;
        atomicAdd(&ws[(bid & (NSLOTS - 1)) * 16], bt);
        __threadfence();                               // slot-add visible before ticket
        const unsigned t = atomicAdd((unsigned*)(ws + 1024), 1u);
        lastflag = (t == NBLOCKS - 1) ? 1 : 0;
    }
    __syncthreads();
    if (lastflag && ty == 0) {                         // one wave of the last block
        __threadfence();
        float v = atomicAdd(&ws[tx * 16], 0.0f);       // coherent read (device scope)
        #pragma unroll
        for (int off = 32; off > 0; off >>= 1)
            v += __shfl_down(v, off, 64);
        if (tx == 0)
            out[0] = v * (1.0f / 81688800.0f);         // 80 * 1011 * 1010
    }
}

extern "C" void kernel_launch(void* const* d_in, const int* in_sizes, int n_in,
                              void* d_out, int out_size, void* d_ws, size_t ws_size,
                              hipStream_t stream) {
    const float* img1 = (const float*)d_in[0];
    const float* img2 = (const float*)d_in[1];
    float* out = (float*)d_out;
    float* ws = (float*)d_ws;

    GK gk;
    for (int i = 0; i < 7; ++i) {
        const double d = i - 3;
        gk.gh[i] = (float)std::exp(-(d * d) / 8.0);
        gk.gv[i] = (float)(std::exp(-(d * d) / 8.0) / (8.0 * M_PI));
    }

    // zero the 64 slots (stride-16 floats) + ticket counter at ws[1024]
    hipMemsetAsync(d_ws, 0, (1024 + 1) * sizeof(float), stream);
    dim3 block(64, 4);
    dim3 grid(16, 64);   // 1024 blocks
    mind_tile<<<grid, block, 0, stream>>>(img1, img2, ws, out, gk);
}

// Round 9
// 71.433 us; speedup vs baseline: 1.2062x; 1.2062x over previous
//
#include <hip/hip_runtime.h>
#include <cmath>

#define IMG_W 1024
#define SROWS 22              // staged source rows  (16 outputs + 6 halo)
#define SCOLS 70              // staged source cols  (64 outputs + 6 halo)

// separable Gaussian: w(ky,kx) = gv[ky]*gh[kx], 1/(8*pi) folded into gv
struct GK { float gh[7]; float gv[7]; };

__device__ __forceinline__ float4 pointwise(const float* __restrict__ img1,
                                            const float* __restrict__ img2,
                                            int sr, int sc)
{
    const int srp = sr ^ 512;               // the only in-bounds y-shift source
    const int scp = sc ^ 512;               // the only in-bounds x-shift source
    const float a  = img2[sr  * IMG_W + sc ];
    const float b  = img2[sr  * IMG_W + scp];
    const float cc = img2[srp * IMG_W + sc ];
    const float d  = img2[srp * IMG_W + scp];
    const float u  = img1[sr  * IMG_W + sc ];
    const float ub = img1[sr  * IMG_W + scp];
    const float uc = img1[srp * IMG_W + sc ];
    const float a2 = a * a;
    const float tb = a - b, tc = a - cc, td = a - d;
    const float su = u - ub, sv = u - uc;
    float4 f;
    f.x = fmaf(tb, tb, -a2);                      // H: (a-ax)^2 - a^2
    f.y = fmaf(tc, tc, -a2);                      // V
    f.z = fmaf(td, td, -a2);                      // D
    f.w = fmaf(u, u + u, fmaf(su, su, sv * sv));  // U (4*Vimg integrand)
    return f;
}

__global__ __launch_bounds__(256)
void mind_tile(const float* __restrict__ img1, const float* __restrict__ img2,
               float* __restrict__ partials, GK gk)
{
    __shared__ float4 s1[SROWS * SCOLS];    // 24640 B -> all 1024 blocks co-resident

    const int tx  = (int)threadIdx.x;       // 0..63 : output col owner
    const int ty  = (int)threadIdx.y;       // 0..3  : wave id / 4-row group owner
    const int tid = ty * 64 + tx;
    // XOR swizzle: boundary-straddling blocks (raw bx==7 / by==31) get raw
    // index 0 -> dispatched first; they run the heavier general path and
    // bound the makespan of the (fully co-resident) grid.
    const int bx  = (int)blockIdx.x ^ 7;
    const int by  = (int)blockIdx.y ^ 31;
    const int x0  = 7 + 64 * bx;            // first output col of tile
    const int y0  = 7 + 16 * by;            // first output row of tile

    // ---- stage 1: pointwise fields -> LDS (shift-indexed, coalesced) ----
    #pragma unroll
    for (int k = 0; k < 6; ++k) {
        const int e = tid + 256 * k;        // over the 22x64 main region
        if (e < SROWS * 64) {
            const int r = e >> 6, c = e & 63;
            const int sr = min(y0 - 3 + r, 1023);   // clamp feeds only masked outputs
            const int sc = min(x0 - 3 + c, 1023);
            s1[r * SCOLS + c] = pointwise(img1, img2, sr, sc);
        }
    }
    {   // halo cols 64..69: one round, threads mapped 8-wide per row
        const int r = tid >> 3, c6 = tid & 7;
        if (r < SROWS && c6 < 6) {
            const int sr = min(y0 - 3 + r, 1023);
            const int sc = min(x0 + 61 + c6, 1023);
            s1[r * SCOLS + 64 + c6] = pointwise(img1, img2, sr, sc);
        }
    }
    __syncthreads();

    // boundary-straddling detection (mask flips between col/row 511 and 512)
    const bool xs = (x0 - 3 <= 511) && (x0 + 66 >= 512);   // raw bx==7 only
    const bool ys = (y0 - 3 <= 511) && (y0 + 18 >= 512);   // raw by==31 only
    const bool xok = (x0 + tx <= 1016);
    float tsum = 0.f;

    if (!xs && !ys) {
        // ============ FAST path (92%): block-uniform masks, one-stage ==========
        float Px[4] = {0,0,0,0}, Py[4] = {0,0,0,0}, Pd[4] = {0,0,0,0}, V4[4] = {0,0,0,0};
        #pragma unroll
        for (int r = 0; r < 10; ++r) {
            const float4* __restrict__ row = &s1[(4 * ty + r) * SCOLS + tx];
            float hH = 0, hV = 0, hD = 0, hU = 0;
            #pragma unroll
            for (int kx = 0; kx < 7; ++kx) {
                const float4 g = row[kx];               // ds_read_b128 imm offset
                hH = fmaf(gk.gh[kx], g.x, hH);
                hV = fmaf(gk.gh[kx], g.y, hV);
                hD = fmaf(gk.gh[kx], g.z, hD);
                hU = fmaf(gk.gh[kx], g.w, hU);
            }
            #pragma unroll
            for (int o = 0; o < 4; ++o) {
                if (r - o >= 0 && r - o <= 6) {          // compile-time pruned
                    const float g = gk.gv[r - o];
                    Px[o] = fmaf(g, hH, Px[o]);
                    Py[o] = fmaf(g, hV, Py[o]);
                    Pd[o] = fmaf(g, hD, Pd[o]);
                    V4[o] = fmaf(g, hU, V4[o]);
                }
            }
        }
        #pragma unroll
        for (int o = 0; o < 4; ++o) {
            const float V = fmaf(V4[o], 0.25f, 1e-5f);
            const float invV = 1.0f / V;
            float M = fminf(0.f, Px[o]);
            M = fminf(M, Py[o]); M = fminf(M, Pd[o]);
            // 5 of 8 near-shift maps equal T0 here -> join the 72 far shifts
            const float pix = 77.f * __expf(M * invV)
                + __expf((M - Px[o]) * invV)
                + __expf((M - Py[o]) * invV)
                + __expf((M - Pd[o]) * invV);
            const bool ok = xok && (y0 + 4 * ty + o <= 1017);
            tsum += ok ? pix : 0.f;
        }
    } else {
        // ============ GENERAL path (79 blocks): per-lane premasked weights =====
        float glx[7], ghx[7];
        #pragma unroll
        for (int kx = 0; kx < 7; ++kx) {
            const bool lo = (((x0 - 3 + tx + kx) & 512) == 0);
            glx[kx] = lo ? gk.gh[kx] : 0.f;
            ghx[kx] = lo ? 0.f : gk.gh[kx];
        }
        float Ph[4]  = {0,0,0,0}, Qh[4]  = {0,0,0,0}, Pv[4] = {0,0,0,0}, Qv[4] = {0,0,0,0};
        float Ppp[4] = {0,0,0,0}, Ppm[4] = {0,0,0,0}, Pmp[4] = {0,0,0,0}, Pmm[4] = {0,0,0,0};
        float V4[4]  = {0,0,0,0};
        #pragma unroll
        for (int r = 0; r < 10; ++r) {
            const float4* __restrict__ row = &s1[(4 * ty + r) * SCOLS + tx];
            float hHlo = 0, hHhi = 0, hV = 0, hDlo = 0, hDhi = 0, hU = 0;
            #pragma unroll
            for (int kx = 0; kx < 7; ++kx) {
                const float4 g = row[kx];
                hHlo = fmaf(glx[kx],   g.x, hHlo);
                hHhi = fmaf(ghx[kx],   g.x, hHhi);
                hV   = fmaf(gk.gh[kx], g.y, hV);
                hDlo = fmaf(glx[kx],   g.z, hDlo);
                hDhi = fmaf(ghx[kx],   g.z, hDhi);
                hU   = fmaf(gk.gh[kx], g.w, hU);
            }
            const bool ylo = (((y0 + 4 * ty - 3 + r) & 512) == 0);
            #pragma unroll
            for (int o = 0; o < 4; ++o) {
                if (r - o >= 0 && r - o <= 6) {
                    const float g  = gk.gv[r - o];
                    const float wl = ylo ? g : 0.f;
                    const float wh = ylo ? 0.f : g;
                    Ph [o] = fmaf(g,  hHlo, Ph [o]);
                    Qh [o] = fmaf(g,  hHhi, Qh [o]);
                    Pv [o] = fmaf(wl, hV,   Pv [o]);
                    Qv [o] = fmaf(wh, hV,   Qv [o]);
                    Ppp[o] = fmaf(wl, hDlo, Ppp[o]);
                    Ppm[o] = fmaf(wh, hDlo, Ppm[o]);
                    Pmp[o] = fmaf(wl, hDhi, Pmp[o]);
                    Pmm[o] = fmaf(wh, hDhi, Pmm[o]);
                    V4 [o] = fmaf(g,  hU,   V4 [o]);
                }
            }
        }
        #pragma unroll
        for (int o = 0; o < 4; ++o) {
            const float V = fmaf(V4[o], 0.25f, 1e-5f);
            const float invV = 1.0f / V;
            float M = fminf(0.f, Ph[o]);
            M = fminf(M, Qh[o]);  M = fminf(M, Pv[o]);  M = fminf(M, Qv[o]);
            M = fminf(M, Ppp[o]); M = fminf(M, Pmp[o]); M = fminf(M, Ppm[o]); M = fminf(M, Pmm[o]);
            const float pix = 72.f * __expf(M * invV)
                + __expf((M - Ph [o]) * invV) + __expf((M - Qh [o]) * invV)
                + __expf((M - Pv [o]) * invV) + __expf((M - Qv [o]) * invV)
                + __expf((M - Ppp[o]) * invV) + __expf((M - Pmp[o]) * invV)
                + __expf((M - Ppm[o]) * invV) + __expf((M - Pmm[o]) * invV);
            const bool ok = xok && (y0 + 4 * ty + o <= 1017);
            tsum += ok ? pix : 0.f;
        }
    }

    // ---- block reduction -> per-block partial (no grid atomics) ----
    #pragma unroll
    for (int off = 32; off > 0; off >>= 1)
        tsum += __shfl_down(tsum, off, 64);
    __shared__ float wsum[4];
    if (tx == 0) wsum[ty] = tsum;
    __syncthreads();
    if (tid == 0)
        partials[(int)blockIdx.y * gridDim.x + (int)blockIdx.x]
            = wsum[0] + wsum[1] + wsum[2] + wsum[3];
}

__global__ __launch_bounds__(256)
void mind_reduce(const float* __restrict__ partials, float* __restrict__ out)
{
    float s = 0.f;
    #pragma unroll
    for (int k = 0; k < 4; ++k)
        s += partials[(int)threadIdx.x + 256 * k];
    double d = (double)s;
    #pragma unroll
    for (int off = 32; off > 0; off >>= 1)
        d += __shfl_down(d, off, 64);
    __shared__ double sm[4];
    const int lane = (int)threadIdx.x & 63, wid = (int)threadIdx.x >> 6;
    if (lane == 0) sm[wid] = d;
    __syncthreads();
    if (threadIdx.x == 0)
        out[0] = (float)((sm[0] + sm[1] + sm[2] + sm[3]) / 81688800.0);  // 80*1011*1010
}

extern "C" void kernel_launch(void* const* d_in, const int* in_sizes, int n_in,
                              void* d_out, int out_size, void* d_ws, size_t ws_size,
                              hipStream_t stream) {
    const float* img1 = (const float*)d_in[0];
    const float* img2 = (const float*)d_in[1];
    float* out = (float*)d_out;
    float* partials = (float*)d_ws;

    GK gk;
    for (int i = 0; i < 7; ++i) {
        const double d = i - 3;
        gk.gh[i] = (float)std::exp(-(d * d) / 8.0);
        gk.gv[i] = (float)(std::exp(-(d * d) / 8.0) / (8.0 * M_PI));
    }

    dim3 block(64, 4);
    dim3 grid(16, 64);   // 1024 blocks, all co-resident (24.6 KB LDS, 4 waves)
    mind_tile<<<grid, block, 0, stream>>>(img1, img2, partials, gk);
    mind_reduce<<<1, 256, 0, stream>>>(partials, out);
}

// Round 10
// 71.408 us; speedup vs baseline: 1.2066x; 1.0003x over previous
//
#include <hip/hip_runtime.h>
#include <cmath>

#define IMG_W 1024
#define TROWS 24              // output rows per tile
#define SROWS 30              // staged source rows  (24 outputs + 6 halo)
#define SCOLS 70              // staged source cols  (64 outputs + 6 halo)

// separable Gaussian: w(ky,kx) = gv[ky]*gh[kx], 1/(8*pi) folded into gv
struct GK { float gh[7]; float gv[7]; };

__global__ __launch_bounds__(256)
void mind_tile(const float* __restrict__ img1, const float* __restrict__ img2,
               float* __restrict__ partials, GK gk)
{
    __shared__ float4 s1[SROWS * SCOLS];    // 33600 B -> 4 blocks/CU capacity

    const int tx  = (int)threadIdx.x;       // 0..63 : output col owner
    const int ty  = (int)threadIdx.y;       // 0..3  : wave id / 6-row group owner
    const int tid = ty * 64 + tx;
    const int x0  = 7 + 64 * (int)blockIdx.x;    // first output col of tile
    const int y0  = 7 + TROWS * (int)blockIdx.y; // first output row of tile

    // ---- stage 1: pointwise fields -> LDS, float4-vectorized ----
    // main region: 30 rows x 16 groups of 4 cols = 480 jobs
    #pragma unroll
    for (int k = 0; k < 2; ++k) {
        const int j = tid + 256 * k;
        if (j < SROWS * 16) {
            const int r  = j >> 4;                  // 0..29
            const int cg = (j & 15) << 2;           // 0,4,...,60
            const int sr = min(y0 - 3 + r, 1023);   // clamp feeds only masked rows
            const int srp = sr ^ 512;               // only in-bounds y-shift source
            const int sc = min(x0 - 3 + cg, 1020);  // 4-aligned; clamp -> masked cols
            const int scp = sc ^ 512;               // 4-aligned, in [0,1020]
            const float4 a  = *(const float4*)(img2 + sr  * IMG_W + sc );
            const float4 b  = *(const float4*)(img2 + sr  * IMG_W + scp);
            const float4 c  = *(const float4*)(img2 + srp * IMG_W + sc );
            const float4 d  = *(const float4*)(img2 + srp * IMG_W + scp);
            const float4 u  = *(const float4*)(img1 + sr  * IMG_W + sc );
            const float4 ub = *(const float4*)(img1 + sr  * IMG_W + scp);
            const float4 uc = *(const float4*)(img1 + srp * IMG_W + sc );
            const float* ap = (const float*)&a;  const float* bp = (const float*)&b;
            const float* cp = (const float*)&c;  const float* dp = (const float*)&d;
            const float* up = (const float*)&u;  const float* ubp = (const float*)&ub;
            const float* ucp = (const float*)&uc;
            #pragma unroll
            for (int i = 0; i < 4; ++i) {
                const float a2 = ap[i] * ap[i];
                const float tb = ap[i] - bp[i], tc = ap[i] - cp[i], td = ap[i] - dp[i];
                const float su = up[i] - ubp[i], sv = up[i] - ucp[i];
                float4 f;
                f.x = fmaf(tb, tb, -a2);                            // H
                f.y = fmaf(tc, tc, -a2);                            // V
                f.z = fmaf(td, td, -a2);                            // D
                f.w = fmaf(up[i], up[i] + up[i], fmaf(su, su, sv * sv)); // U
                s1[r * SCOLS + cg + i] = f;
            }
        }
    }
    {   // halo cols 64..69 (scalar): 30 rows x 6 cols, threads mapped 8-wide
        const int r = tid >> 3, c6 = tid & 7;
        if (r < SROWS && c6 < 6) {
            const int sr = min(y0 - 3 + r, 1023);
            const int srp = sr ^ 512;
            const int sc = min(x0 + 61 + c6, 1023);
            const int scp = sc ^ 512;
            const float a  = img2[sr  * IMG_W + sc ];
            const float b  = img2[sr  * IMG_W + scp];
            const float c  = img2[srp * IMG_W + sc ];
            const float d  = img2[srp * IMG_W + scp];
            const float u  = img1[sr  * IMG_W + sc ];
            const float ub = img1[sr  * IMG_W + scp];
            const float uc = img1[srp * IMG_W + sc ];
            const float a2 = a * a;
            const float tb = a - b, tc = a - c, td = a - d;
            const float su = u - ub, sv = u - uc;
            float4 f;
            f.x = fmaf(tb, tb, -a2);
            f.y = fmaf(tc, tc, -a2);
            f.z = fmaf(td, td, -a2);
            f.w = fmaf(u, u + u, fmaf(su, su, sv * sv));
            s1[r * SCOLS + 64 + c6] = f;
        }
    }
    __syncthreads();

    // boundary-straddling detection (mask flips between col/row 511 and 512)
    const bool xs = (x0 - 3 <= 511) && (x0 + 66 >= 512);
    const bool ys = (y0 - 3 <= 511) && (y0 + 26 >= 512);
    const bool xok = (x0 + tx <= 1016);
    float tsum = 0.f;

    if (!xs && !ys) {
        // ============ FAST path: block-uniform masks ==========
        float Px[6] = {0,0,0,0,0,0}, Py[6] = {0,0,0,0,0,0},
              Pd[6] = {0,0,0,0,0,0}, V4[6] = {0,0,0,0,0,0};
        #pragma unroll
        for (int r = 0; r < 12; ++r) {
            const float4* __restrict__ row = &s1[(6 * ty + r) * SCOLS + tx];
            float hH = 0, hV = 0, hD = 0, hU = 0;
            #pragma unroll
            for (int kx = 0; kx < 7; ++kx) {
                const float4 g = row[kx];               // ds_read_b128 imm offset
                hH = fmaf(gk.gh[kx], g.x, hH);
                hV = fmaf(gk.gh[kx], g.y, hV);
                hD = fmaf(gk.gh[kx], g.z, hD);
                hU = fmaf(gk.gh[kx], g.w, hU);
            }
            #pragma unroll
            for (int o = 0; o < 6; ++o) {
                if (r - o >= 0 && r - o <= 6) {          // compile-time pruned
                    const float g = gk.gv[r - o];
                    Px[o] = fmaf(g, hH, Px[o]);
                    Py[o] = fmaf(g, hV, Py[o]);
                    Pd[o] = fmaf(g, hD, Pd[o]);
                    V4[o] = fmaf(g, hU, V4[o]);
                }
            }
        }
        #pragma unroll
        for (int o = 0; o < 6; ++o) {
            const float V = fmaf(V4[o], 0.25f, 1e-5f);
            const float invV = 1.0f / V;
            float M = fminf(0.f, Px[o]);
            M = fminf(M, Py[o]); M = fminf(M, Pd[o]);
            // 5 of 8 near-shift maps equal T0 here -> join the 72 far shifts
            const float pix = 77.f * __expf(M * invV)
                + __expf((M - Px[o]) * invV)
                + __expf((M - Py[o]) * invV)
                + __expf((M - Pd[o]) * invV);
            const bool ok = xok && (y0 + 6 * ty + o <= 1017);
            tsum += ok ? pix : 0.f;
        }
    } else {
        // ============ GENERAL path: per-lane premasked weights ==========
        float glx[7], ghx[7];
        #pragma unroll
        for (int kx = 0; kx < 7; ++kx) {
            const bool lo = (((x0 - 3 + tx + kx) & 512) == 0);
            glx[kx] = lo ? gk.gh[kx] : 0.f;
            ghx[kx] = lo ? 0.f : gk.gh[kx];
        }
        float Ph[6]  = {0,0,0,0,0,0}, Qh[6]  = {0,0,0,0,0,0};
        float Pv[6]  = {0,0,0,0,0,0}, Qv[6]  = {0,0,0,0,0,0};
        float Ppp[6] = {0,0,0,0,0,0}, Ppm[6] = {0,0,0,0,0,0};
        float Pmp[6] = {0,0,0,0,0,0}, Pmm[6] = {0,0,0,0,0,0};
        float V4[6]  = {0,0,0,0,0,0};
        #pragma unroll
        for (int r = 0; r < 12; ++r) {
            const float4* __restrict__ row = &s1[(6 * ty + r) * SCOLS + tx];
            float hHlo = 0, hHhi = 0, hV = 0, hDlo = 0, hDhi = 0, hU = 0;
            #pragma unroll
            for (int kx = 0; kx < 7; ++kx) {
                const float4 g = row[kx];
                hHlo = fmaf(glx[kx],   g.x, hHlo);
                hHhi = fmaf(ghx[kx],   g.x, hHhi);
                hV   = fmaf(gk.gh[kx], g.y, hV);
                hDlo = fmaf(glx[kx],   g.z, hDlo);
                hDhi = fmaf(ghx[kx],   g.z, hDhi);
                hU   = fmaf(gk.gh[kx], g.w, hU);
            }
            const bool ylo = (((y0 + 6 * ty - 3 + r) & 512) == 0);  // wave-uniform
            #pragma unroll
            for (int o = 0; o < 6; ++o) {
                if (r - o >= 0 && r - o <= 6) {
                    const float g  = gk.gv[r - o];
                    const float wl = ylo ? g : 0.f;
                    const float wh = ylo ? 0.f : g;
                    Ph [o] = fmaf(g,  hHlo, Ph [o]);
                    Qh [o] = fmaf(g,  hHhi, Qh [o]);
                    Pv [o] = fmaf(wl, hV,   Pv [o]);
                    Qv [o] = fmaf(wh, hV,   Qv [o]);
                    Ppp[o] = fmaf(wl, hDlo, Ppp[o]);
                    Ppm[o] = fmaf(wh, hDlo, Ppm[o]);
                    Pmp[o] = fmaf(wl, hDhi, Pmp[o]);
                    Pmm[o] = fmaf(wh, hDhi, Pmm[o]);
                    V4 [o] = fmaf(g,  hU,   V4 [o]);
                }
            }
        }
        #pragma unroll
        for (int o = 0; o < 6; ++o) {
            const float V = fmaf(V4[o], 0.25f, 1e-5f);
            const float invV = 1.0f / V;
            float M = fminf(0.f, Ph[o]);
            M = fminf(M, Qh[o]);  M = fminf(M, Pv[o]);  M = fminf(M, Qv[o]);
            M = fminf(M, Ppp[o]); M = fminf(M, Pmp[o]); M = fminf(M, Ppm[o]); M = fminf(M, Pmm[o]);
            const float pix = 72.f * __expf(M * invV)
                + __expf((M - Ph [o]) * invV) + __expf((M - Qh [o]) * invV)
                + __expf((M - Pv [o]) * invV) + __expf((M - Qv [o]) * invV)
                + __expf((M - Ppp[o]) * invV) + __expf((M - Pmp[o]) * invV)
                + __expf((M - Ppm[o]) * invV) + __expf((M - Pmm[o]) * invV);
            const bool ok = xok && (y0 + 6 * ty + o <= 1017);
            tsum += ok ? pix : 0.f;
        }
    }

    // ---- block reduction -> per-block partial (no grid atomics) ----
    #pragma unroll
    for (int off = 32; off > 0; off >>= 1)
        tsum += __shfl_down(tsum, off, 64);
    __shared__ float wsum[4];
    if (tx == 0) wsum[ty] = tsum;
    __syncthreads();
    if (tid == 0)
        partials[(int)blockIdx.y * gridDim.x + (int)blockIdx.x]
            = wsum[0] + wsum[1] + wsum[2] + wsum[3];
}

__global__ __launch_bounds__(256)
void mind_reduce(const float* __restrict__ partials, int n, float* __restrict__ out)
{
    float s = 0.f;
    #pragma unroll
    for (int k = 0; k < 3; ++k) {
        const int i = (int)threadIdx.x + 256 * k;
        s += (i < n) ? partials[i] : 0.f;
    }
    double d = (double)s;
    #pragma unroll
    for (int off = 32; off > 0; off >>= 1)
        d += __shfl_down(d, off, 64);
    __shared__ double sm[4];
    const int lane = (int)threadIdx.x & 63, wid = (int)threadIdx.x >> 6;
    if (lane == 0) sm[wid] = d;
    __syncthreads();
    if (threadIdx.x == 0)
        out[0] = (float)((sm[0] + sm[1] + sm[2] + sm[3]) / 81688800.0);  // 80*1011*1010
}

extern "C" void kernel_launch(void* const* d_in, const int* in_sizes, int n_in,
                              void* d_out, int out_size, void* d_ws, size_t ws_size,
                              hipStream_t stream) {
    const float* img1 = (const float*)d_in[0];
    const float* img2 = (const float*)d_in[1];
    float* out = (float*)d_out;
    float* partials = (float*)d_ws;

    GK gk;
    for (int i = 0; i < 7; ++i) {
        const double d = i - 3;
        gk.gh[i] = (float)std::exp(-(d * d) / 8.0);
        gk.gv[i] = (float)(std::exp(-(d * d) / 8.0) / (8.0 * M_PI));
    }

    dim3 block(64, 4);
    dim3 grid(16, 43);   // 16*64=1024 >= 1010 cols ; 43*24=1032 >= 1011 rows
    mind_tile<<<grid, block, 0, stream>>>(img1, img2, partials, gk);
    mind_reduce<<<1, 256, 0, stream>>>(partials, 16 * 43, out);
}